// Round 1
// baseline (406.396 us; speedup 1.0000x reference)
//
#include <hip/hip_runtime.h>

// BTT layer: M=N=A=B_BLK=64, RANK=8, rows=4096, features=4096.
// Stage 1 (per n): inner[n,B,j] = sum_b x[B, n*64+b] * btt_r[n,b,j],  j = m*8+r
//   stored permuted to ws as inner_p[m][B][n*8+r]  (bf16)
// Stage 2 (per m): out[B, m*64+a] = sum_k inner_p[m,B,k] * btt_l[m,k,a] + bias

typedef float f32x4 __attribute__((ext_vector_type(4)));
typedef short short8 __attribute__((ext_vector_type(8)));

static __device__ __forceinline__ unsigned short f2b(float f) {
    union { float f; unsigned u; } a; a.f = f;
    unsigned u = a.u;
    unsigned r = u + 0x7fffu + ((u >> 16) & 1u);   // round-to-nearest-even
    return (unsigned short)(r >> 16);
}

#define LD1 72   // padded LDS stride (144 B, 16B-aligned, breaks bank aliasing)

// ---------------- Kernel 1: batched GEMM over n, K=64, fused permute ----------------
// grid: (4 j-tiles, Bc/128 row-tiles, 64 n)   block: 256
__global__ __launch_bounds__(256) void btt_k1(
    const float* __restrict__ x,        // [4096][4096]
    const float* __restrict__ btt_r,    // [64][64][512]
    unsigned short* __restrict__ inner, // [64][Bc][512] bf16 (permuted layout)
    int row0, int Bc)
{
    __shared__ unsigned short smem[2 * 128 * LD1];
    unsigned short* As = smem;                 // [128 rows][64 k] stride LD1
    unsigned short* Bs = smem + 128 * LD1;     // [128 j][64 k]   stride LD1

    const int tid = threadIdx.x;
    const int jt  = blockIdx.x;   // 0..3
    const int bt  = blockIdx.y;
    const int n   = blockIdx.z;

    // ---- stage A: x tile (128 rows x 64 cols), fp32 -> bf16
    {
        const float* xp = x + (size_t)(row0 + bt * 128) * 4096 + n * 64;
        #pragma unroll
        for (int p = 0; p < 8; ++p) {
            int idx = p * 256 + tid;          // 0..2047
            int rl  = idx >> 4;               // 0..127
            int c4  = (idx & 15) << 2;        // 0..60
            float4 v = *(const float4*)(xp + (size_t)rl * 4096 + c4);
            ushort4 u;
            u.x = f2b(v.x); u.y = f2b(v.y); u.z = f2b(v.z); u.w = f2b(v.w);
            *(ushort4*)&As[rl * LD1 + c4] = u;
        }
    }
    // ---- stage B: R_n[b][j] -> Bs[j_local][b] (transpose), fp32 -> bf16
    {
        const float* rp = btt_r + (size_t)n * 64 * 512 + jt * 128;
        #pragma unroll
        for (int p = 0; p < 8; ++p) {
            int idx = p * 256 + tid;          // 0..2047
            int b   = idx >> 5;               // 0..63
            int jg  = (idx & 31) << 2;        // 0..124
            float4 v = *(const float4*)(rp + (size_t)b * 512 + jg);
            Bs[(jg + 0) * LD1 + b] = f2b(v.x);
            Bs[(jg + 1) * LD1 + b] = f2b(v.y);
            Bs[(jg + 2) * LD1 + b] = f2b(v.z);
            Bs[(jg + 3) * LD1 + b] = f2b(v.w);
        }
    }
    __syncthreads();

    const int wid  = tid >> 6;
    const int lane = tid & 63;
    const int quad = lane >> 4;
    const int lr   = lane & 15;
    const int wrow = (wid >> 1) * 64;
    const int wcol = (wid & 1) * 64;

    f32x4 acc[4][4];
    #pragma unroll
    for (int i = 0; i < 4; ++i)
        #pragma unroll
        for (int j = 0; j < 4; ++j)
            acc[i][j] = (f32x4){0.f, 0.f, 0.f, 0.f};

    #pragma unroll
    for (int kk = 0; kk < 2; ++kk) {
        const int ko = kk * 32 + quad * 8;
        short8 a[4], b[4];
        #pragma unroll
        for (int i = 0; i < 4; ++i)
            a[i] = *(const short8*)&As[(wrow + i * 16 + lr) * LD1 + ko];
        #pragma unroll
        for (int j = 0; j < 4; ++j)
            b[j] = *(const short8*)&Bs[(wcol + j * 16 + lr) * LD1 + ko];
        #pragma unroll
        for (int i = 0; i < 4; ++i)
            #pragma unroll
            for (int j = 0; j < 4; ++j)
                acc[i][j] = __builtin_amdgcn_mfma_f32_16x16x32_bf16(a[i], b[j], acc[i][j], 0, 0, 0);
    }

    __syncthreads();
    // ---- epilogue: transpose through LDS, store permuted bf16 16B chunks
    unsigned short* Cs = smem;                 // [128][136] : 17408 <= 18432 ok
    #pragma unroll
    for (int i = 0; i < 4; ++i)
        #pragma unroll
        for (int j = 0; j < 4; ++j)
            #pragma unroll
            for (int t = 0; t < 4; ++t) {
                int row = wrow + i * 16 + quad * 4 + t;
                int col = wcol + j * 16 + lr;
                Cs[row * 136 + col] = f2b(acc[i][j][t]);
            }
    __syncthreads();
    {
        #pragma unroll
        for (int p = 0; p < 8; ++p) {
            int idx = p * 256 + tid;          // 0..2047
            int rl  = idx >> 4;               // row 0..127
            int g   = idx & 15;               // j8-group 0..15
            int m   = jt * 16 + g;            // global m
            size_t off = ((size_t)m * Bc + (bt * 128 + rl)) * 512 + n * 8;
            *(uint4*)&inner[off] = *(const uint4*)&Cs[rl * 136 + g * 8];
        }
    }
}

// ---------------- Kernel 2: batched GEMM over m, K=512 ----------------
// grid: (Bc/128 row-tiles, 64 m)   block: 256
__global__ __launch_bounds__(256) void btt_k2(
    const unsigned short* __restrict__ inner, // [64][Bc][512] bf16
    const float* __restrict__ btt_l,          // [64][512][64]
    const float* __restrict__ bias,           // [4096]
    float* __restrict__ out,                  // [4096][4096]
    int row0, int Bc)
{
    __shared__ unsigned short As[128 * LD1];  // [128 rows][64 k]
    __shared__ unsigned short Ls[64 * LD1];   // [64 a][64 k]

    const int tid = threadIdx.x;
    const int bt  = blockIdx.x;
    const int m   = blockIdx.y;

    const int wid  = tid >> 6;
    const int lane = tid & 63;
    const int quad = lane >> 4;
    const int lr   = lane & 15;
    const int wrow = (wid >> 1) * 64;
    const int wcol = (wid & 1) * 32;

    f32x4 acc[4][2];
    #pragma unroll
    for (int i = 0; i < 4; ++i)
        #pragma unroll
        for (int j = 0; j < 2; ++j)
            acc[i][j] = (f32x4){0.f, 0.f, 0.f, 0.f};

    const unsigned short* ap = inner + ((size_t)m * Bc + bt * 128) * 512;
    const float* lp = btt_l + (size_t)m * 512 * 64;

    for (int it = 0; it < 8; ++it) {
        const int k0 = it * 64;
        // stage A: 128 rows x 64 k bf16, 16B vector copies
        #pragma unroll
        for (int p = 0; p < 4; ++p) {
            int idx = p * 256 + tid;          // 0..1023
            int rl  = idx >> 3;               // 0..127
            int g   = (idx & 7) << 3;         // 0..56
            *(uint4*)&As[rl * LD1 + g] = *(const uint4*)(ap + (size_t)rl * 512 + k0 + g);
        }
        // stage L: btt_l[m][k][a] -> Ls[a][k_local] (transpose), fp32 -> bf16
        #pragma unroll
        for (int p = 0; p < 4; ++p) {
            int idx = p * 256 + tid;          // 0..1023
            int kl  = idx >> 4;               // 0..63
            int ag  = (idx & 15) << 2;        // 0..60
            float4 v = *(const float4*)(lp + (size_t)(k0 + kl) * 64 + ag);
            Ls[(ag + 0) * LD1 + kl] = f2b(v.x);
            Ls[(ag + 1) * LD1 + kl] = f2b(v.y);
            Ls[(ag + 2) * LD1 + kl] = f2b(v.z);
            Ls[(ag + 3) * LD1 + kl] = f2b(v.w);
        }
        __syncthreads();

        #pragma unroll
        for (int kk = 0; kk < 2; ++kk) {
            const int ko = kk * 32 + quad * 8;
            short8 a[4], b[2];
            #pragma unroll
            for (int i = 0; i < 4; ++i)
                a[i] = *(const short8*)&As[(wrow + i * 16 + lr) * LD1 + ko];
            #pragma unroll
            for (int j = 0; j < 2; ++j)
                b[j] = *(const short8*)&Ls[(wcol + j * 16 + lr) * LD1 + ko];
            #pragma unroll
            for (int i = 0; i < 4; ++i)
                #pragma unroll
                for (int j = 0; j < 2; ++j)
                    acc[i][j] = __builtin_amdgcn_mfma_f32_16x16x32_bf16(a[i], b[j], acc[i][j], 0, 0, 0);
        }
        __syncthreads();
    }

    // ---- epilogue: fp32 + bias
    const int rowbase = row0 + bt * 128 + wrow;
    #pragma unroll
    for (int j = 0; j < 2; ++j) {
        int col = m * 64 + wcol + j * 16 + lr;
        float bv = bias[col];
        #pragma unroll
        for (int i = 0; i < 4; ++i)
            #pragma unroll
            for (int t = 0; t < 4; ++t) {
                int row = rowbase + i * 16 + quad * 4 + t;
                out[(size_t)row * 4096 + col] = acc[i][j][t] + bv;
            }
    }
}

extern "C" void kernel_launch(void* const* d_in, const int* in_sizes, int n_in,
                              void* d_out, int out_size, void* d_ws, size_t ws_size,
                              hipStream_t stream) {
    const float* x    = (const float*)d_in[0];
    const float* r    = (const float*)d_in[1];
    const float* l    = (const float*)d_in[2];
    const float* bias = (const float*)d_in[3];
    float* out = (float*)d_out;
    unsigned short* inner = (unsigned short*)d_ws;

    const int rows = in_sizes[0] / 4096;   // 4096

    // Chunk the batch so the bf16 intermediate fits ws (and ideally L3).
    int Bc = 1024;
    while (Bc > 128 && (size_t)64 * Bc * 512 * sizeof(unsigned short) > ws_size) Bc >>= 1;
    if (Bc > rows) Bc = rows;

    for (int row0 = 0; row0 < rows; row0 += Bc) {
        dim3 g1(4, Bc / 128, 64);
        btt_k1<<<g1, dim3(256), 0, stream>>>(x, r, inner, row0, Bc);
        dim3 g2(Bc / 128, 64);
        btt_k2<<<g2, dim3(256), 0, stream>>>(inner, l, bias, out, row0, Bc);
    }
}

// Round 2
// 306.123 us; speedup vs baseline: 1.3276x; 1.3276x over previous
//
#include <hip/hip_runtime.h>

// BTT(4096->4096, m=n=a=b=64, rank=8) == dense 4096x4096 matmul:
//   W[n*64+b][m*64+a] = sum_r R[n,b,m*8+r] * L[m,n*8+r,a]
//   out = x @ W + bias
// Pipeline: prep_w (W^T bf16, 32MB) + prep_x (x bf16, 32MB) + one m97-style GEMM.

typedef float f32x4 __attribute__((ext_vector_type(4)));
typedef short short8 __attribute__((ext_vector_type(8)));

static __device__ __forceinline__ unsigned short f2b(float f) {
    union { float f; unsigned u; } a; a.f = f;
    unsigned u = a.u;
    unsigned r = u + 0x7fffu + ((u >> 16) & 1u);   // RNE
    return (unsigned short)(r >> 16);
}

static __device__ __forceinline__ void load_lds_16(const void* gptr, void* lptr) {
    __builtin_amdgcn_global_load_lds(
        (const __attribute__((address_space(1))) unsigned int*)gptr,
        (__attribute__((address_space(3))) unsigned int*)lptr, 16, 0, 0);
}

// ---------------- prep_w: Wt[ma][nb] bf16 = compose R,L over rank ----------------
// grid (64 m, 64 n), block 256
__global__ __launch_bounds__(256) void prep_w(
    const float* __restrict__ btt_r,   // [64][64][512]
    const float* __restrict__ btt_l,   // [64][512][64]
    unsigned short* __restrict__ Wt)   // [4096][4096] bf16, Wt[ma][nb]
{
    __shared__ float Rs[64][8];   // R[n][b][m*8+r] slice
    __shared__ float Ls[8][64];   // L[m][n*8+r][a] slice (512 contiguous floats)

    const int m = blockIdx.x, n = blockIdx.y, tid = threadIdx.x;

    if (tid < 128) {
        int b = tid >> 1, rh = (tid & 1) * 4;
        float4 v = *(const float4*)(btt_r + (size_t)n * 32768 + (size_t)b * 512 + m * 8 + rh);
        *(float4*)&Rs[b][rh] = v;
    } else {
        int t2 = (tid - 128) * 4;
        float4 v = *(const float4*)(btt_l + (size_t)m * 32768 + n * 512 + t2);
        *(float4*)&(&Ls[0][0])[t2] = v;
    }
    __syncthreads();

    const int a  = tid >> 2;
    const int bg = (tid & 3) * 16;
    float la[8];
    #pragma unroll
    for (int r = 0; r < 8; ++r) la[r] = Ls[r][a];

    unsigned short o[16];
    #pragma unroll
    for (int bb = 0; bb < 16; ++bb) {
        float acc = 0.f;
        #pragma unroll
        for (int r = 0; r < 8; ++r) acc += Rs[bg + bb][r] * la[r];
        o[bb] = f2b(acc);
    }
    size_t off = (size_t)(m * 64 + a) * 4096 + n * 64 + bg;
    *(uint4*)&Wt[off]     = *(const uint4*)&o[0];
    *(uint4*)&Wt[off + 8] = *(const uint4*)&o[8];
}

// ---------------- prep_x: fp32 -> bf16, 8 elems/thread ----------------
__global__ __launch_bounds__(256) void prep_x(
    const float* __restrict__ x, unsigned short* __restrict__ xb, int total8)
{
    int i = blockIdx.x * 256 + threadIdx.x;
    if (i >= total8) return;
    size_t off = (size_t)i * 8;
    float4 v0 = *(const float4*)(x + off);
    float4 v1 = *(const float4*)(x + off + 4);
    unsigned short o[8];
    o[0] = f2b(v0.x); o[1] = f2b(v0.y); o[2] = f2b(v0.z); o[3] = f2b(v0.w);
    o[4] = f2b(v1.x); o[5] = f2b(v1.y); o[6] = f2b(v1.z); o[7] = f2b(v1.w);
    *(uint4*)(xb + off) = *(const uint4*)o;
}

// ---------------- gemm: out[row][col] = sum_k xb[row][k]*Wt[col][k] + bias[col] ----
// 128x128 tile, BK=64, global_load_lds w=16, XOR-swizzled LDS granules.
// grid (32 colTiles, 32 rowTiles), block 256 (4 waves, each 64x64)
__global__ __launch_bounds__(256) void gemm_btt(
    const unsigned short* __restrict__ xb,   // [4096][4096] bf16
    const unsigned short* __restrict__ Wt,   // [4096][4096] bf16 [col][k]
    const float* __restrict__ bias,          // [4096]
    float* __restrict__ out)                 // [4096][4096] fp32
{
    __shared__ unsigned short As[128 * 64];  // [row][granule g: 8 bf16], g holds src granule g^(row&7)
    __shared__ unsigned short Bs[128 * 64];

    const int tid = threadIdx.x;
    const int colbase = blockIdx.x * 128;
    const int rowbase = blockIdx.y * 128;

    const int wid  = tid >> 6;
    const int lane = tid & 63;
    const int quad = lane >> 4;
    const int lr   = lane & 15;
    const int wrow = (wid >> 1) * 64;
    const int wcol = (wid & 1) * 64;

    f32x4 acc[4][4];
    #pragma unroll
    for (int i = 0; i < 4; ++i)
        #pragma unroll
        for (int j = 0; j < 4; ++j)
            acc[i][j] = (f32x4){0.f, 0.f, 0.f, 0.f};

    // per-thread staging descriptor: granule o = p*256+tid, row = o>>3, slot g = o&7
    int srow[4], sg[4];
    #pragma unroll
    for (int p = 0; p < 4; ++p) {
        int o = p * 256 + tid;
        srow[p] = o >> 3;
        sg[p]   = (o & 7) ^ (srow[p] & 7);   // source granule for this slot
    }

    for (int it = 0; it < 64; ++it) {
        const int k0 = it * 64;
        #pragma unroll
        for (int p = 0; p < 4; ++p) {
            int o = p * 256 + tid;
            load_lds_16(xb + (size_t)(rowbase + srow[p]) * 4096 + k0 + sg[p] * 8, &As[o * 8]);
            load_lds_16(Wt + (size_t)(colbase + srow[p]) * 4096 + k0 + sg[p] * 8, &Bs[o * 8]);
        }
        __syncthreads();

        #pragma unroll
        for (int kk = 0; kk < 2; ++kk) {
            const int kg = kk * 4 + quad;
            short8 a[4], b[4];
            #pragma unroll
            for (int i = 0; i < 4; ++i) {
                int r = wrow + i * 16 + lr;
                a[i] = *(const short8*)&As[r * 64 + (kg ^ (lr & 7)) * 8];
            }
            #pragma unroll
            for (int j = 0; j < 4; ++j) {
                int r = wcol + j * 16 + lr;
                b[j] = *(const short8*)&Bs[r * 64 + (kg ^ (lr & 7)) * 8];
            }
            #pragma unroll
            for (int i = 0; i < 4; ++i)
                #pragma unroll
                for (int j = 0; j < 4; ++j)
                    acc[i][j] = __builtin_amdgcn_mfma_f32_16x16x32_bf16(a[i], b[j], acc[i][j], 0, 0, 0);
        }
        __syncthreads();
    }

    #pragma unroll
    for (int j = 0; j < 4; ++j) {
        const int col = colbase + wcol + j * 16 + lr;
        const float bv = bias[col];
        #pragma unroll
        for (int i = 0; i < 4; ++i) {
            const int row = rowbase + wrow + i * 16 + quad * 4;
            #pragma unroll
            for (int t = 0; t < 4; ++t)
                out[(size_t)(row + t) * 4096 + col] = acc[i][j][t] + bv;
        }
    }
}

extern "C" void kernel_launch(void* const* d_in, const int* in_sizes, int n_in,
                              void* d_out, int out_size, void* d_ws, size_t ws_size,
                              hipStream_t stream) {
    const float* x    = (const float*)d_in[0];
    const float* r    = (const float*)d_in[1];
    const float* l    = (const float*)d_in[2];
    const float* bias = (const float*)d_in[3];
    float* out = (float*)d_out;

    unsigned short* xb = (unsigned short*)d_ws;                      // 32 MB
    unsigned short* Wt = (unsigned short*)d_ws + (size_t)4096 * 4096; // 32 MB

    const int rows = in_sizes[0] / 4096;   // 4096
    const int total8 = rows * 4096 / 8;

    prep_w<<<dim3(64, 64), dim3(256), 0, stream>>>(r, l, Wt);
    prep_x<<<dim3(total8 / 256), dim3(256), 0, stream>>>(x, xb, total8);
    gemm_btt<<<dim3(32, rows / 128), dim3(256), 0, stream>>>(xb, Wt, bias, out);
}